// Round 10
// baseline (120.337 us; speedup 1.0000x reference)
//
#include <hip/hip_runtime.h>
#include <math.h>

#define HH 512
#define WW 512
#define NB 8
#define NC 3
#define HW (HH*WW)

#define RSTRIP 8                          // output rows per wave
#define CSTRIP 62                         // output cols per wave
#define NROWS (HH/RSTRIP)                 // 64
#define NCOLS ((WW + CSTRIP - 1)/CSTRIP)  // 9
#define WPB 4                             // waves per block

typedef float float4u __attribute__((ext_vector_type(4), aligned(4)));

// ---- single-channel row load (9 taps) into named regs V[0..8] ----
#define LOADROW1(RR, V) do {                                                  \
    const int r_ = (RR);                                                      \
    if ((unsigned)r_ < (unsigned)HH) {                                        \
        if (csafe) {                                                          \
            const float* rp_ = ip + (size_t)r_ * WW + (size_t)(cl - 4);       \
            float4u p_ = *(const float4u*)rp_;                                \
            float4u q_ = *(const float4u*)(rp_ + 4);                          \
            V[0]=p_[0]; V[1]=p_[1]; V[2]=p_[2]; V[3]=p_[3];                   \
            V[4]=q_[0]; V[5]=q_[1]; V[6]=q_[2]; V[7]=q_[3];                   \
            V[8]=rp_[8];                                                      \
        } else {                                                              \
            const size_t rw_ = (size_t)r_ * WW;                               \
            _Pragma("unroll")                                                 \
            for (int k = 0; k < 9; ++k) {                                     \
                int cc_ = cl - 4 + k;                                         \
                bool m_ = ((unsigned)cc_ < (unsigned)WW);                     \
                int ci_ = cc_ < 0 ? 0 : (cc_ > WW - 1 ? WW - 1 : cc_);        \
                V[k] = m_ ? ip[rw_ + ci_] : 0.0f;                             \
            }                                                                 \
        }                                                                     \
    } else {                                                                  \
        _Pragma("unroll")                                                     \
        for (int k = 0; k < 9; ++k) V[k] = 0.0f;                              \
    }                                                                         \
} while (0)

// ---- compute phase PH (literal): H from V; V-blur at PH>=8; sobel at PH>=10 ----
#define CPH(PH, V) do {                                                       \
    { double a_ = 0.0;                                                        \
      _Pragma("unroll")                                                       \
      for (int k = 0; k < 9; ++k) a_ = fma(g[k], (double)V[k], a_);           \
      hb[(PH) % 9] = a_; }                                                    \
    if ((PH) >= 8) {                                                          \
        double c_ = 0.0;                                                      \
        _Pragma("unroll")                                                     \
        for (int k = 0; k < 9; ++k)                                           \
            c_ = fma(g[k], hb[((PH) + 1 + k) % 9], c_);                       \
        vr[(PH) % 3] = c_; }                                                  \
    if ((PH) >= 10) {                                                         \
        const int ri_ = R0 - 10 + (PH);                                       \
        const bool up_ = (ri_ >= 1), dn_ = (ri_ <= HH - 2);                   \
        double top_ = up_ ? vr[((PH) - 2) % 3] : 0.0;                         \
        double mid_ =       vr[((PH) - 1) % 3];                               \
        double bot_ = dn_ ? vr[(PH) % 3]       : 0.0;                         \
        double s_ = top_ + 2.0 * mid_ + bot_;                                 \
        double d_ = top_ - bot_;                                              \
        double sL_ = __shfl_up(s_, 1), sR_ = __shfl_down(s_, 1);              \
        double dL_ = __shfl_up(d_, 1), dR_ = __shfl_down(d_, 1);              \
        sL_ = cml ? sL_ : 0.0;  sR_ = cmr ? sR_ : 0.0;                        \
        dL_ = cml ? dL_ : 0.0;  dR_ = cmr ? dR_ : 0.0;                        \
        double gx_ = sL_ - sR_;                                               \
        double gy_ = dL_ + 2.0 * d_ + dR_;                                    \
        accM[(PH) - 10] += sqrt(gx_ * gx_ + gy_ * gy_);                       \
        accX[(PH) - 10] += gx_;                                               \
        accY[(PH) - 10] += gy_; }                                             \
} while (0)

// K1: register row-streaming separable conv; one wave per 62x8 strip, 4 waves
// per block, channel-sequential passes (keeps pipeline state <=128 VGPR).
// Per pass: prefetch row r+1's 9 taps (2xdwordx4+dword) before row r's f64
// H/V/sobel tail -> VMEM latency hidden. Cross-channel sums accumulate in
// registers in channel order (bit-identical to the proven all-channel form).
__global__ __launch_bounds__(256) void canny_gm_kernel(
    const float* __restrict__ img, const float* __restrict__ gwin,
    float* __restrict__ GM, unsigned char* __restrict__ KP)
{
    const int lane = threadIdx.x & 63;
    const int wv   = threadIdx.x >> 6;         // 0..3
    const int cs   = blockIdx.x % NCOLS;
    const int rs   = (blockIdx.x / NCOLS) * WPB + wv;
    const int b    = blockIdx.y;

    const int R0 = rs * RSTRIP;
    const int cl = cs * CSTRIP - 1 + lane;     // this lane's blur column

    double g[9];
#pragma unroll
    for (int k = 0; k < 9; ++k) g[k] = (double)gwin[k];

    const bool csafe = (cs >= 1) && (cs <= NCOLS - 2);
    const bool lane_out = (lane >= 1) && (lane <= CSTRIP) && (cl < WW);
    const bool cml = ((unsigned)(cl - 1) < (unsigned)WW);
    const bool cmr = ((unsigned)(cl + 1) < (unsigned)WW);

    double accM[RSTRIP], accX[RSTRIP], accY[RSTRIP];
#pragma unroll
    for (int i = 0; i < RSTRIP; ++i) { accM[i] = 0.0; accX[i] = 0.0; accY[i] = 0.0; }

    double hb[9];    // h-blur ring: row R0-5+ph -> slot ph%9 (self-initializing)
    double vr[3];    // v-blur ring: row R0-9+ph -> slot ph%3

#pragma unroll 1
    for (int c = 0; c < NC; ++c) {
        const float* ip = img + ((size_t)b * NC + c) * HW;
        float A[9], B[9];

        LOADROW1(R0 - 5, A);
        LOADROW1(R0 - 4, B);  CPH(0,  A);
        LOADROW1(R0 - 3, A);  CPH(1,  B);
        LOADROW1(R0 - 2, B);  CPH(2,  A);
        LOADROW1(R0 - 1, A);  CPH(3,  B);
        LOADROW1(R0 + 0, B);  CPH(4,  A);
        LOADROW1(R0 + 1, A);  CPH(5,  B);
        LOADROW1(R0 + 2, B);  CPH(6,  A);
        LOADROW1(R0 + 3, A);  CPH(7,  B);
        LOADROW1(R0 + 4, B);  CPH(8,  A);
        LOADROW1(R0 + 5, A);  CPH(9,  B);
        LOADROW1(R0 + 6, B);  CPH(10, A);
        LOADROW1(R0 + 7, A);  CPH(11, B);
        LOADROW1(R0 + 8, B);  CPH(12, A);
        LOADROW1(R0 + 9, A);  CPH(13, B);
        LOADROW1(R0 +10, B);  CPH(14, A);
        LOADROW1(R0 +11, A);  CPH(15, B);
        LOADROW1(R0 +12, B);  CPH(16, A);
                              CPH(17, B);
    }

    // ---- write GM (f32) + sector from f64 channel sums
    const double t225 = 0.41421356237309503;   // tan(22.5 deg)
    const double t675 = 2.414213562373095;     // tan(67.5 deg)
    if (lane_out) {
#pragma unroll
        for (int i = 0; i < RSTRIP; ++i) {
            size_t o = (size_t)b * HW + (size_t)(R0 + i) * WW + cl;
            GM[o] = (float)accM[i];
            double sx = accX[i], sy = accY[i];
            double ax = fabs(sx), ay = fabs(sy);
            int kp;
            if (ay <= ax * t225)      kp = (sx >= 0.0) ? 4 : 0;
            else if (ay >= ax * t675) kp = (sy > 0.0) ? 6 : 2;
            else if (sx > 0.0)        kp = (sy > 0.0) ? 5 : 3;
            else                      kp = (sy > 0.0) ? 7 : 1;
            KP[o] = (unsigned char)kp;
        }
    }
}

// K23 fused: per 32x32 tile, compute the 34x34 halo of CODE bytes into LDS
// (thin/threshold decisions in f64 from f32 GM), then hysteresis.
// code bit0: thin > 0.3 ; bit1: 0.1 <= thin <= 0.3
__global__ __launch_bounds__(256) void canny_thin_out_kernel(
    const float* __restrict__ GM, const unsigned char* __restrict__ KP,
    float* __restrict__ out)
{
    __shared__ unsigned char scode[34 * 35];

    const int tilesX = WW / 32;                 // 16
    const int tx0 = (blockIdx.x % tilesX) * 32;
    const int ty0 = (blockIdx.x / tilesX) * 32;
    const int b = blockIdx.y;
    const int t = threadIdx.x;

    // dr+1 per b (digits b7..b0): 0,0,0,1,2,2,2,1 ; dc+1: 2,1,0,0,0,1,2,2
    const int dr = (int)((0x00012221u >> (b * 4)) & 15u) - 1;
    const int dc = (int)((0x21000122u >> (b * 4)) & 15u) - 1;

    // ---- phase 1: codes for tile+halo (34x34 items, width-34 walk)
    {
        int r = t / 34, cc = t % 34, idx = t;
#pragma unroll
        for (int it = 0; it < 5; ++it) {
            if (idx < 34 * 34) {
                int gi = ty0 - 1 + r, gj = tx0 - 1 + cc;
                unsigned char code = 0;
                if ((unsigned)gi < (unsigned)HH && (unsigned)gj < (unsigned)WW) {
                    size_t p0 = (size_t)gi * WW + gj;
                    int kp = KP[(size_t)b * HW + p0];
                    int kn = (kp + 4) & 7;
                    int ni = gi + dr, nj = gj + dc;
                    bool nin = ((unsigned)ni < (unsigned)HH) && ((unsigned)nj < (unsigned)WW);
                    size_t pn = (size_t)ni * WW + nj;
                    double gmp  = (double)GM[(size_t)kp * HW + p0];
                    double gmn  = (double)GM[(size_t)kn * HW + p0];
                    double gmpn = nin ? (double)GM[(size_t)kp * HW + pn] : 0.0;
                    double gmnn = nin ? (double)GM[(size_t)kn * HW + pn] : 0.0;
                    double pos = gmp - gmpn;
                    double neg = gmn - gmnn;
                    double thin = (fmin(pos, neg) > 0.0) ? (double)GM[(size_t)b * HW + p0] : 0.0;
                    if (thin > 0.3) code |= 1;
                    if (thin >= 0.1 && thin <= 0.3) code |= 2;
                }
                scode[r * 35 + cc] = code;
            }
            idx += 256; r += 7; cc += 18;        // 256 = 7*34 + 18
            if (cc >= 34) { cc -= 34; ++r; }
        }
    }
    __syncthreads();

    // ---- phase 2: hysteresis + border zero, 4 px/thread
#pragma unroll
    for (int p = 0; p < 4; ++p) {
        int pix = t + p * 256;
        int i = pix >> 5, j = pix & 31;
        int gi = ty0 + i, gj = tx0 + j;
        float res = 0.0f;
        if (gi > 0 && gi < HH - 1 && gj > 0 && gj < WW - 1) {
            const unsigned char* sc = scode + (i + 1) * 35 + (j + 1);
            unsigned char c = *sc;
            if (c & 1) {
                res = 1.0f;
            } else if (c & 2) {
                int any = 0;
                any |= sc[-36] & 1; any |= sc[-35] & 1; any |= sc[-34] & 1;
                any |= sc[-1]  & 1; any |= sc[ 1]  & 1;
                any |= sc[ 34] & 1; any |= sc[ 35] & 1; any |= sc[ 36] & 1;
                if (any) res = 1.0f;
            }
        }
        out[(size_t)b * HW + (size_t)gi * WW + gj] = res;
    }
}

extern "C" void kernel_launch(void* const* d_in, const int* in_sizes, int n_in,
                              void* d_out, int out_size, void* d_ws, size_t ws_size,
                              hipStream_t stream) {
    const float* img  = (const float*)d_in[0];
    const float* gwin = (const float*)d_in[1];

    float* GM = (float*)d_ws;                                   // 8 MB
    unsigned char* KP = (unsigned char*)d_ws + (size_t)NB * HW * sizeof(float);
    float* out = (float*)d_out;

    dim3 g1(NCOLS * (NROWS / WPB), NB);   // (144, 8) = 1152 blocks x 256 thr
    canny_gm_kernel<<<g1, 256, 0, stream>>>(img, gwin, GM, KP);

    dim3 g2((WW / 32) * (HH / 32), NB);   // (256, 8) blocks x 256
    canny_thin_out_kernel<<<g2, 256, 0, stream>>>(GM, KP, out);
}

// Round 12
// 70.081 us; speedup vs baseline: 1.7171x; 1.7171x over previous
//
#include <hip/hip_runtime.h>
#include <math.h>

#define HH 512
#define WW 512
#define NB 8
#define NC 3
#define HW (HH*WW)

#define RSTRIP 16                         // output rows per wave
#define CSTRIP 62                        // output cols per wave
#define NROWS (HH/RSTRIP)                 // 32
#define NCOLS ((WW + CSTRIP - 1)/CSTRIP)  // 9
#define WPB 2                             // waves per block

// K1: register row-streaming separable conv; one 64-lane wave per 62x16 strip,
// 2 independent waves/block. f64 compute end-to-end (proven bit-safe); GM
// stored f32 (proven safe r8-r10). gk-folded column masks (r7-proven);
// 3-chunk 26-phase driver (r4-proven ring algebra).
__global__ __launch_bounds__(128) void canny_gm_kernel(
    const float* __restrict__ img, const float* __restrict__ gwin,
    float* __restrict__ GM, unsigned char* __restrict__ KP)
{
    const int lane = threadIdx.x & 63;
    const int wv   = threadIdx.x >> 6;         // 0..1
    const int cs   = blockIdx.x % NCOLS;
    const int rs   = (blockIdx.x / NCOLS) * WPB + wv;
    const int b    = blockIdx.y;

    const int R0 = rs * RSTRIP;
    const int cl = cs * CSTRIP - 1 + lane;     // this lane's blur column

    double g[9];
#pragma unroll
    for (int k = 0; k < 9; ++k) g[k] = (double)gwin[k];

    // 9-tap column window: clamped indices; mask folded into per-lane coeffs
    int cidx[9]; double gk[9];
#pragma unroll
    for (int k = 0; k < 9; ++k) {
        int cc = cl - 4 + k;
        bool m = ((unsigned)cc < (unsigned)WW);
        gk[k] = m ? g[k] : 0.0;                // 0*finite = +/-0 -> acc unchanged
        int cc2 = cc < 0 ? 0 : cc;
        cidx[k] = cc2 > (WW - 1) ? (WW - 1) : cc2;
    }
    const bool lane_out = (lane >= 1) && (lane <= CSTRIP) && (cl < WW);
    const bool cml = ((unsigned)(cl - 1) < (unsigned)WW);
    const bool cmr = ((unsigned)(cl + 1) < (unsigned)WW);

    const float* ip0 = img + ((size_t)b * NC + 0) * HW;
    const float* ip1 = img + ((size_t)b * NC + 1) * HW;
    const float* ip2 = img + ((size_t)b * NC + 2) * HW;

    double hb[3][9];   // h-blur ring: global phase p -> slot p%9
    double vb[3][3];   // v-blur ring: row x -> slot (x-R0+2)%3
#pragma unroll
    for (int c = 0; c < 3; ++c) {
#pragma unroll
        for (int k = 0; k < 9; ++k) hb[c][k] = 0.0;
#pragma unroll
        for (int k = 0; k < 3; ++k) vb[c][k] = 0.0;
    }

    const double t225 = 0.41421356237309503;   // tan(22.5 deg)
    const double t675 = 2.414213562373095;     // tan(67.5 deg)

    auto PHASE = [&](int r, int ph, bool doV, bool doS) {
        // ---- h-blur of img row r -> hb[c][ph] (zero outside image)
        if ((unsigned)r < (unsigned)HH) {
            const size_t ro = (size_t)r * WW;
            float v0[9], v1[9], v2[9];
#pragma unroll
            for (int k = 0; k < 9; ++k) {
                v0[k] = ip0[ro + cidx[k]];
                v1[k] = ip1[ro + cidx[k]];
                v2[k] = ip2[ro + cidx[k]];
            }
            double a0 = 0.0, a1 = 0.0, a2 = 0.0;
#pragma unroll
            for (int k = 0; k < 9; ++k) {
                a0 = fma(gk[k], (double)v0[k], a0);
                a1 = fma(gk[k], (double)v1[k], a1);
                a2 = fma(gk[k], (double)v2[k], a2);
            }
            hb[0][ph] = a0; hb[1][ph] = a1; hb[2][ph] = a2;
        } else {
            hb[0][ph] = 0.0; hb[1][ph] = 0.0; hb[2][ph] = 0.0;
        }

        // ---- v-blur row rv = r-4 -> vb[c][(ph+2)%3]; tap r-8+k in slot (ph+1+k)%9
        if (doV) {
#pragma unroll
            for (int c = 0; c < 3; ++c) {
                double acc = 0.0;
#pragma unroll
                for (int k = 0; k < 9; ++k)
                    acc = fma(g[k], hb[c][(ph + 1 + k) % 9], acc);
                vb[c][(ph + 2) % 3] = acc;
            }
        }

        // ---- sobel + GM/sector at row ri = r-5
        if (doS) {
            const int ri = r - 5;
            const bool up = (ri >= 1), dn = (ri <= HH - 2);
            double mag = 0.0, sgx = 0.0, sgy = 0.0;
#pragma unroll
            for (int c = 0; c < 3; ++c) {
                double top = up ? vb[c][ph % 3]       : 0.0;  // row ri-1
                double mid =      vb[c][(ph + 1) % 3];        // row ri
                double bot = dn ? vb[c][(ph + 2) % 3] : 0.0;  // row ri+1
                double s = top + 2.0 * mid + bot;   // [1,2,1] column sum
                double d = top - bot;               // vertical diff
                double sL = __shfl_up(s, 1), sR = __shfl_down(s, 1);
                double dL = __shfl_up(d, 1), dR = __shfl_down(d, 1);
                sL = cml ? sL : 0.0;  sR = cmr ? sR : 0.0;
                dL = cml ? dL : 0.0;  dR = cmr ? dR : 0.0;
                double gx = sL - sR;
                double gy = dL + 2.0 * d + dR;
                mag += sqrt(gx * gx + gy * gy);
                sgx += gx; sgy += gy;
            }
            if (lane_out) {
                size_t o = (size_t)b * HW + (size_t)ri * WW + cl;
                GM[o] = (float)mag;
                double ax = fabs(sgx), ay = fabs(sgy);
                int kp;
                if (ay <= ax * t225)      kp = (sgx >= 0.0) ? 4 : 0;
                else if (ay >= ax * t675) kp = (sgy > 0.0) ? 6 : 2;
                else if (sgx > 0.0)       kp = (sgy > 0.0) ? 5 : 3;
                else                      kp = (sgy > 0.0) ? 7 : 1;
                KP[o] = (unsigned char)kp;
            }
        }
    };

    // chunk 0: rows R0-5 .. R0+3 — H; V starts at ph 8 (rv = R0-1)
    {
        const int rb = R0 - 5;
#pragma unroll
        for (int ph = 0; ph < 9; ++ph) PHASE(rb + ph, ph, ph == 8, false);
    }
    // chunk 1: rows R0+4 .. R0+12 — H+V; S from ph 1 (ri = R0 .. R0+7)
    {
        const int rb = R0 + 4;
#pragma unroll
        for (int ph = 0; ph < 9; ++ph) PHASE(rb + ph, ph, true, ph >= 1);
    }
    // chunk 2: rows R0+13 .. R0+20 — H+V+S (ri = R0+8 .. R0+15)
    {
        const int rb = R0 + 13;
#pragma unroll
        for (int ph = 0; ph < 8; ++ph) PHASE(rb + ph, ph, true, true);
    }
}

// K23 fused: per 32x32 tile, compute the 34x34 halo of CODE bytes into LDS
// (thin/threshold decisions in f64 from f32 GM -- exact), then hysteresis.
// code bit0: thin > 0.3 ; bit1: 0.1 <= thin <= 0.3
__global__ __launch_bounds__(256) void canny_thin_out_kernel(
    const float* __restrict__ GM, const unsigned char* __restrict__ KP,
    float* __restrict__ out)
{
    __shared__ unsigned char scode[34 * 35];

    const int tilesX = WW / 32;                 // 16
    const int tx0 = (blockIdx.x % tilesX) * 32;
    const int ty0 = (blockIdx.x / tilesX) * 32;
    const int b = blockIdx.y;
    const int t = threadIdx.x;

    // dr+1 per b (digits b7..b0): 0,0,0,1,2,2,2,1 ; dc+1: 2,1,0,0,0,1,2,2
    const int dr = (int)((0x00012221u >> (b * 4)) & 15u) - 1;
    const int dc = (int)((0x21000122u >> (b * 4)) & 15u) - 1;

    // ---- phase 1: codes for tile+halo (34x34 items, width-34 walk)
    {
        int r = t / 34, cc = t % 34, idx = t;
#pragma unroll
        for (int it = 0; it < 5; ++it) {
            if (idx < 34 * 34) {
                int gi = ty0 - 1 + r, gj = tx0 - 1 + cc;
                unsigned char code = 0;
                if ((unsigned)gi < (unsigned)HH && (unsigned)gj < (unsigned)WW) {
                    size_t p0 = (size_t)gi * WW + gj;
                    int kp = KP[(size_t)b * HW + p0];
                    int kn = (kp + 4) & 7;
                    int ni = gi + dr, nj = gj + dc;
                    bool nin = ((unsigned)ni < (unsigned)HH) && ((unsigned)nj < (unsigned)WW);
                    size_t pn = (size_t)ni * WW + nj;
                    double gmp  = (double)GM[(size_t)kp * HW + p0];
                    double gmn  = (double)GM[(size_t)kn * HW + p0];
                    double gmpn = nin ? (double)GM[(size_t)kp * HW + pn] : 0.0;
                    double gmnn = nin ? (double)GM[(size_t)kn * HW + pn] : 0.0;
                    double pos = gmp - gmpn;
                    double neg = gmn - gmnn;
                    double thin = (fmin(pos, neg) > 0.0) ? (double)GM[(size_t)b * HW + p0] : 0.0;
                    if (thin > 0.3) code |= 1;
                    if (thin >= 0.1 && thin <= 0.3) code |= 2;
                }
                scode[r * 35 + cc] = code;
            }
            idx += 256; r += 7; cc += 18;        // 256 = 7*34 + 18
            if (cc >= 34) { cc -= 34; ++r; }
        }
    }
    __syncthreads();

    // ---- phase 2: hysteresis + border zero, 4 px/thread
#pragma unroll
    for (int p = 0; p < 4; ++p) {
        int pix = t + p * 256;
        int i = pix >> 5, j = pix & 31;
        int gi = ty0 + i, gj = tx0 + j;
        float res = 0.0f;
        if (gi > 0 && gi < HH - 1 && gj > 0 && gj < WW - 1) {
            const unsigned char* sc = scode + (i + 1) * 35 + (j + 1);
            unsigned char c = *sc;
            if (c & 1) {
                res = 1.0f;
            } else if (c & 2) {
                int any = 0;
                any |= sc[-36] & 1; any |= sc[-35] & 1; any |= sc[-34] & 1;
                any |= sc[-1]  & 1; any |= sc[ 1]  & 1;
                any |= sc[ 34] & 1; any |= sc[ 35] & 1; any |= sc[ 36] & 1;
                if (any) res = 1.0f;
            }
        }
        out[(size_t)b * HW + (size_t)gi * WW + gj] = res;
    }
}

extern "C" void kernel_launch(void* const* d_in, const int* in_sizes, int n_in,
                              void* d_out, int out_size, void* d_ws, size_t ws_size,
                              hipStream_t stream) {
    const float* img  = (const float*)d_in[0];
    const float* gwin = (const float*)d_in[1];

    float* GM = (float*)d_ws;                                   // 8 MB
    unsigned char* KP = (unsigned char*)d_ws + (size_t)NB * HW * sizeof(float);
    float* out = (float*)d_out;

    dim3 g1(NCOLS * (NROWS / WPB), NB);   // (144, 8) = 1152 blocks x 128 thr
    canny_gm_kernel<<<g1, 128, 0, stream>>>(img, gwin, GM, KP);

    dim3 g2((WW / 32) * (HH / 32), NB);   // (256, 8) blocks x 256
    canny_thin_out_kernel<<<g2, 256, 0, stream>>>(GM, KP, out);
}